// Round 6
// baseline (303.119 us; speedup 1.0000x reference)
//
#include <hip/hip_runtime.h>

typedef __bf16 bf16x8 __attribute__((ext_vector_type(8)));
typedef float f32x4 __attribute__((ext_vector_type(4)));
typedef unsigned short us8 __attribute__((ext_vector_type(8)));

#define PI_F 3.14159265358979323846f

__device__ __forceinline__ unsigned short f2bf(float f) {
    unsigned u = __float_as_uint(f);
    u += 0x7FFFu + ((u >> 16) & 1u);   // RNE
    return (unsigned short)(u >> 16);
}
__device__ __forceinline__ float bf2f(unsigned short h) {
    return __uint_as_float(((unsigned)h) << 16);
}

__device__ __forceinline__ void async16(const void* g, void* l) {
    __builtin_amdgcn_global_load_lds(
        (const __attribute__((address_space(1))) unsigned int*)g,
        (__attribute__((address_space(3))) unsigned int*)l, 16, 0, 0);
}

// ---------------------------------------------------------------------------
// Merged weight prep.
// idx < 1M : W1b[(k*8+h)*1024 + d] = bf16( W_proj[h,k,d] * cos(pi*freq[h,k]) )
// else     : Wob[n*1024 + (k*8+h)] = bf16( out_W[n, h*128+k] )
__global__ __launch_bounds__(256) void prep_k(const float* __restrict__ W,
                                              const float* __restrict__ fr,
                                              const float* __restrict__ Wo,
                                              unsigned short* __restrict__ W1b,
                                              unsigned short* __restrict__ Wob) {
    int idx = blockIdx.x * 256 + threadIdx.x;      // 2M
    if (idx < (1 << 20)) {
        int n = idx >> 10, d = idx & 1023;
        int k = n >> 3, h = n & 7;
        float c = cosf(fr[h * 128 + k] * PI_F);
        W1b[idx] = f2bf(W[((h * 128 + k) << 10) + d] * c);
    } else {
        int i2 = idx - (1 << 20);
        int n = i2 >> 10, dp = i2 & 1023;
        int k = dp >> 3, h = dp & 7;
        Wob[i2] = f2bf(Wo[(n << 10) + h * 128 + k]);
    }
}

// ---------------------------------------------------------------------------
// x -> bf16 cast + per-(b,d) partial column sums via PLAIN stores
// (contiguous per-lane atomicAdd serialized at L2: 121us in round 3).
__global__ __launch_bounds__(256) void xbar_cast(const float* __restrict__ x,
                                                 unsigned short* __restrict__ xb,
                                                 float* __restrict__ part) {
    int bid = blockIdx.x;            // 1024
    int b = bid >> 8;
    int s0 = (bid & 255) * 16;
    int t = threadIdx.x;             // d4 index
    float a0 = 0.f, a1 = 0.f, a2 = 0.f, a3 = 0.f;
    for (int i = 0; i < 16; ++i) {
        long row = (long)b * 4096 + s0 + i;
        float4 v = ((const float4*)x)[row * 256 + t];
        a0 += v.x; a1 += v.y; a2 += v.z; a3 += v.w;
        ushort4 u;
        u.x = f2bf(v.x); u.y = f2bf(v.y); u.z = f2bf(v.z); u.w = f2bf(v.w);
        ((ushort4*)xb)[row * 256 + t] = u;
    }
    float4 p; p.x = a0; p.y = a1; p.z = a2; p.w = a3;
    ((float4*)part)[bid * 256 + t] = p;
}

// Reduce part[1024][1024] -> xbar[4][1024]. 32 blocks, fully coalesced.
__global__ __launch_bounds__(256) void xbar_r(const float* __restrict__ part,
                                              float* __restrict__ xbar) {
    __shared__ float sl[256];
    int blk = blockIdx.x;            // 32 = b*8 + dgrp
    int b = blk >> 3, dgrp = blk & 7;
    int t = threadIdx.x;
    int col = dgrp * 128 + (t & 127);
    int ih = t >> 7;
    float s = 0.f;
    for (int i = 0; i < 128; ++i) {
        int cb = b * 256 + ih * 128 + i;
        s += part[cb * 1024 + col];
    }
    sl[t] = s;
    __syncthreads();
    if (t < 128) xbar[b * 1024 + col] = sl[t] + sl[t + 128];
}

// ---------------------------------------------------------------------------
// summary[b,h,k] = (1/S) * dot(xbar[b,:], W_proj[h,k,:]) * cos(pi*freq[h,k])
__global__ __launch_bounds__(256) void summary_k(const float* __restrict__ xbar,
                                                 const float* __restrict__ W,
                                                 const float* __restrict__ fr,
                                                 float* __restrict__ summary) {
    int wave = (blockIdx.x * 256 + threadIdx.x) >> 6;   // 0..4095 = b*1024+h*128+k
    int lane = threadIdx.x & 63;
    int b = wave >> 10, hk = wave & 1023;
    int h = hk >> 7, k = hk & 127;
    const float* wrow = &W[(h * 128 + k) << 10];
    const float* xrow = &xbar[b << 10];
    float s = 0.f;
    for (int d = lane; d < 1024; d += 64) s += xrow[d] * wrow[d];
    for (int off = 32; off; off >>= 1) s += __shfl_down(s, off);
    if (lane == 0) {
        float c = cosf(fr[h * 128 + k] * PI_F);
        summary[wave] = s * c * (1.0f / 4096.0f);
    }
}

// ---------------------------------------------------------------------------
// pol -> normalize -> dots -> gelu MLP -> softplus -> impedance & coef. 1 block.
__global__ __launch_bounds__(256) void imp_k(const float* __restrict__ summary,
                                             const float* __restrict__ pol_W,
                                             const float* __restrict__ pol_b,
                                             const float* __restrict__ imp_W1,
                                             const float* __restrict__ imp_b1,
                                             const float* __restrict__ imp_W2,
                                             const float* __restrict__ imp_b2,
                                             float* __restrict__ coef_out,
                                             float* __restrict__ imp_out) {
    __shared__ float pol[4][8][32];
    __shared__ float rn[32];
    int t = threadIdx.x;
    for (int o = t; o < 1024; o += 256) {
        int b = o >> 8, h = (o >> 5) & 7, p = o & 31;
        const float* srow = &summary[(b * 8 + h) * 128];
        const float* wrow = &pol_W[(h * 32 + p) * 128];
        float acc = pol_b[h * 32 + p];
        for (int k = 0; k < 128; ++k) acc += srow[k] * wrow[k];
        pol[b][h][p] = tanhf(acc);
    }
    __syncthreads();
    if (t < 32) {
        int b = t >> 3, h = t & 7;
        float ss = 0.f;
        for (int p = 0; p < 32; ++p) { float v = pol[b][h][p]; ss += v * v; }
        rn[t] = 1.0f / fmaxf(sqrtf(ss), 1e-12f);
    }
    __syncthreads();
    {
        int b = t >> 6, i = (t >> 3) & 7, j = t & 7;
        float d = 0.f;
        for (int p = 0; p < 32; ++p) d += pol[b][i][p] * pol[b][j][p];
        d *= rn[b * 8 + i] * rn[b * 8 + j];
        float s = imp_b2[0];
        for (int c = 0; c < 16; ++c) {
            float z = d * imp_W1[c] + imp_b1[c];
            float gl = 0.5f * z * (1.0f + erff(z * 0.70710678118654752f));
            s += gl * imp_W2[c];
        }
        float sp = fmaxf(s, 0.0f) + log1pf(expf(-fabsf(s)));   // softplus
        float impv = (i == j) ? 0.0f : sp;
        imp_out[t] = impv;
        coef_out[t] = (i == j) ? 0.0f : 0.1f / (1.0f + impv);
    }
}

// ---------------------------------------------------------------------------
// XCD-aware block remap (verified: FETCH 132->41 MB): each XCD (n&7) gets a
// contiguous 16-row-band slab; cols iterate slowest.
__device__ __forceinline__ void swizzle_blk(int n, long& rowBase, long& colBase) {
    int xcd = n & 7, s = n >> 3;
    rowBase = (long)(xcd * 16 + (s & 15)) * 128;
    colBase = (long)(s >> 4) * 128;
}

// ---------------------------------------------------------------------------
// Round-1 proven GEMM core: 128x128 tile, BK=32, global_load_lds x16B,
// 4 waves x (4x4) 16x16x32 MFMA. Fused-mix epilogues regressed twice
// (r4: 71us, r5: 82us vs 53us plain — barrier-tail bound); mix is a
// separate streaming kernel again.
__global__ __launch_bounds__(256, 3) void gemm_bt(const unsigned short* __restrict__ A,
                                                  const unsigned short* __restrict__ B,
                                                  unsigned short* __restrict__ C) {
    __shared__ unsigned short As[128 * 32];
    __shared__ unsigned short Bs[128 * 32];
    const int t = threadIdx.x;
    const int wave = t >> 6;
    const int lane = t & 63;
    const int wr = wave >> 1, wc = wave & 1;
    long rowBase, colBase;
    swizzle_blk(blockIdx.x, rowBase, colBase);

    const int lr = lane >> 2;
    const int lb = (lane & 3) * 16;
    const char* gA = (const char*)A + (rowBase + wave * 32 + lr) * 2048 + lb;
    const char* gB = (const char*)B + (colBase + wave * 32 + lr) * 2048 + lb;
    char* lA = (char*)As + wave * 2048;
    char* lB = (char*)Bs + wave * 2048;
    const int q = lane >> 4;
    const int c16 = lane & 15;

    f32x4 acc[4][4] = {};
    for (int kt = 0; kt < 1024; kt += 32) {
        const char* a0 = gA + kt * 2;
        const char* b0 = gB + kt * 2;
        async16(a0, lA);
        async16(a0 + 16 * 2048, lA + 1024);
        async16(b0, lB);
        async16(b0 + 16 * 2048, lB + 1024);
        __syncthreads();
        bf16x8 af[4], bfr[4];
#pragma unroll
        for (int mi = 0; mi < 4; ++mi)
            af[mi] = *(const bf16x8*)((const char*)As + ((wr * 64 + mi * 16 + c16) * 32 + q * 8) * 2);
#pragma unroll
        for (int ni = 0; ni < 4; ++ni)
            bfr[ni] = *(const bf16x8*)((const char*)Bs + ((wc * 64 + ni * 16 + c16) * 32 + q * 8) * 2);
#pragma unroll
        for (int mi = 0; mi < 4; ++mi)
#pragma unroll
            for (int ni = 0; ni < 4; ++ni)
                acc[mi][ni] = __builtin_amdgcn_mfma_f32_16x16x32_bf16(af[mi], bfr[ni], acc[mi][ni], 0, 0, 0);
        __syncthreads();
    }
#pragma unroll
    for (int mi = 0; mi < 4; ++mi) {
#pragma unroll
        for (int ni = 0; ni < 4; ++ni) {
            long col = colBase + wc * 64 + ni * 16 + c16;
            long row0 = rowBase + wr * 64 + mi * 16 + q * 4;
#pragma unroll
            for (int r = 0; r < 4; ++r)
                C[(row0 + r) * 1024 + col] = f2bf(acc[mi][ni][r]);
        }
    }
}

// ---------------------------------------------------------------------------
// Head mixing (separate streaming kernel — round-1 proven). Columns are
// (k,h)-interleaved so the 8 heads of one k-group are 16 contiguous bytes.
// out[i] = v[i] + scale_s * sum_j coef[b,i,j] * v[j].
__global__ __launch_bounds__(256) void mix_k(const unsigned short* __restrict__ heads,
                                             const float* __restrict__ coef,
                                             const int* __restrict__ causal,
                                             unsigned short* __restrict__ merged) {
    __shared__ float cf[256];
    int t = threadIdx.x;
    cf[t] = coef[t];
    __syncthreads();
    long g = (long)blockIdx.x * 256 + t;   // (bs, kgroup)
    long bs = g >> 7;
    int m = (int)(g & 127);
    int b = (int)(bs >> 12);
    int s = (int)(bs & 4095);
    float scale = causal[0] ? (float)(s + 1) * (1.0f / 4096.0f) : 1.0f;
    const ushort4* hp = (const ushort4*)(heads + bs * 1024 + m * 8);
    ushort4 u0 = hp[0], u1 = hp[1];
    float v[8] = {bf2f(u0.x), bf2f(u0.y), bf2f(u0.z), bf2f(u0.w),
                  bf2f(u1.x), bf2f(u1.y), bf2f(u1.z), bf2f(u1.w)};
    const float* cb = cf + b * 64;
    float o[8];
#pragma unroll
    for (int i = 0; i < 8; ++i) {
        float ts = 0.f;
#pragma unroll
        for (int j = 0; j < 8; ++j) ts += cb[i * 8 + j] * v[j];
        o[i] = v[i] + scale * ts;
    }
    ushort4 o0, o1;
    o0.x = f2bf(o[0]); o0.y = f2bf(o[1]); o0.z = f2bf(o[2]); o0.w = f2bf(o[3]);
    o1.x = f2bf(o[4]); o1.y = f2bf(o[5]); o1.z = f2bf(o[6]); o1.w = f2bf(o[7]);
    ushort4* op = (ushort4*)(merged + bs * 1024 + m * 8);
    op[0] = o0; op[1] = o1;
}

// ---------------------------------------------------------------------------
// LayerNorm over D=1024: y = ypre + out_b + x; out = (y-mu)/sqrt(var+eps)*g+b
__global__ __launch_bounds__(256) void ln_k(const unsigned short* __restrict__ ypre,
                                            const float* __restrict__ x,
                                            const float* __restrict__ outb,
                                            const float* __restrict__ gam,
                                            const float* __restrict__ bet,
                                            float* __restrict__ out) {
    int row = blockIdx.x;       // 16384
    int t = threadIdx.x;        // 256, 4 elems each
    long base = (long)row * 1024 + t * 4;
    ushort4 yp = *(const ushort4*)(ypre + base);
    float4 xv = *(const float4*)(x + base);
    float4 bv = *(const float4*)(outb + t * 4);
    float y0 = bf2f(yp.x) + xv.x + bv.x;
    float y1 = bf2f(yp.y) + xv.y + bv.y;
    float y2 = bf2f(yp.z) + xv.z + bv.z;
    float y3 = bf2f(yp.w) + xv.w + bv.w;
    float s = y0 + y1 + y2 + y3;
    float ss = y0 * y0 + y1 * y1 + y2 * y2 + y3 * y3;
    for (int off = 32; off; off >>= 1) {
        s += __shfl_down(s, off);
        ss += __shfl_down(ss, off);
    }
    __shared__ float red[8];
    int wv = t >> 6, ln = t & 63;
    if (ln == 0) { red[wv] = s; red[4 + wv] = ss; }
    __syncthreads();
    float S1 = red[0] + red[1] + red[2] + red[3];
    float S2 = red[4] + red[5] + red[6] + red[7];
    float mu = S1 * (1.0f / 1024.0f);
    float var = S2 * (1.0f / 1024.0f) - mu * mu;
    float rs = 1.0f / sqrtf(var + 1e-5f);
    float4 gv = *(const float4*)(gam + t * 4);
    float4 bb = *(const float4*)(bet + t * 4);
    float4 o;
    o.x = (y0 - mu) * rs * gv.x + bb.x;
    o.y = (y1 - mu) * rs * gv.y + bb.y;
    o.z = (y2 - mu) * rs * gv.z + bb.z;
    o.w = (y3 - mu) * rs * gv.w + bb.w;
    *(float4*)(out + base) = o;
}

// ---------------------------------------------------------------------------
extern "C" void kernel_launch(void* const* d_in, const int* in_sizes, int n_in,
                              void* d_out, int out_size, void* d_ws, size_t ws_size,
                              hipStream_t stream) {
    const float* x       = (const float*)d_in[0];
    const float* W_proj  = (const float*)d_in[1];
    const float* freqs   = (const float*)d_in[2];
    const float* pol_W   = (const float*)d_in[3];
    const float* pol_b   = (const float*)d_in[4];
    const float* imp_W1  = (const float*)d_in[5];
    const float* imp_b1  = (const float*)d_in[6];
    const float* imp_W2  = (const float*)d_in[7];
    const float* imp_b2  = (const float*)d_in[8];
    const float* out_W   = (const float*)d_in[9];
    const float* out_b   = (const float*)d_in[10];
    const float* ln_g    = (const float*)d_in[11];
    const float* ln_b    = (const float*)d_in[12];
    const int*   causal  = (const int*)d_in[13];
    float* out = (float*)d_out;

    char* ws = (char*)d_ws;
    unsigned short* xb      = (unsigned short*)(ws + 0);          // 32MB; dead after gemm1 -> reused as merged
    unsigned short* heads   = (unsigned short*)(ws + 33554432);   // 32MB; dead after mix -> reused as ypre
    unsigned short* w1b     = (unsigned short*)(ws + 67108864);   // 2MB
    unsigned short* wob     = (unsigned short*)(ws + 69206016);   // 2MB
    float* xbar             = (float*)(ws + 71303168);            // 16KB
    float* summary          = (float*)(ws + 71319552);            // 16KB
    float* coef             = (float*)(ws + 71335936);            // 1KB
    float* part             = (float*)heads;                      // 4MB; dead before gemm1 writes heads
    unsigned short* merged  = xb;
    unsigned short* ypre    = heads;

    prep_k<<<8192, 256, 0, stream>>>(W_proj, freqs, out_W, w1b, wob);
    xbar_cast<<<1024, 256, 0, stream>>>(x, xb, part);
    xbar_r<<<32, 256, 0, stream>>>(part, xbar);
    summary_k<<<1024, 256, 0, stream>>>(xbar, W_proj, freqs, summary);
    imp_k<<<1, 256, 0, stream>>>(summary, pol_W, pol_b, imp_W1, imp_b1,
                                 imp_W2, imp_b2, coef, out + 16777216);
    gemm_bt<<<1024, 256, 0, stream>>>(xb, w1b, heads);
    mix_k<<<8192, 256, 0, stream>>>(heads, coef, causal, merged);
    gemm_bt<<<1024, 256, 0, stream>>>(merged, wob, ypre);
    ln_k<<<16384, 256, 0, stream>>>(ypre, x, out_b, ln_g, ln_b, out);
}